// Round 4
// baseline (452.098 us; speedup 1.0000x reference)
//
#include <hip/hip_runtime.h>
#include <hip/hip_bf16.h>

#define Bn   32
#define Cn   512
#define GCn  128
#define HWn  3136
#define M0   128

#define Q_ELEMS  (Bn*GCn*HWn)     // 12845056 bf16 elems
#define KV_ELEMS (Bn*4*32*32)     // 131072 f32
#define KS_ELEMS (Bn*4*32)        // 4096 f32

typedef __attribute__((ext_vector_type(8))) short bf16x8;
typedef __attribute__((ext_vector_type(4))) float f32x4;

__device__ __forceinline__ float bf2f(unsigned short u) {
    union { unsigned int i; float f; } v; v.i = ((unsigned int)u) << 16; return v.f;
}
__device__ __forceinline__ unsigned short f2bf(float f) {
    union { __hip_bfloat16 h; unsigned short u; } v; v.h = __float2bfloat16(f); return v.u;
}
__device__ __forceinline__ float act_elu1(float v) {
    return v > 0.0f ? v + 1.0f : __expf(v);
}

// ---- pre: wfrag swizzle (blocks 0..127) + zero kv/ksum (blocks 128..655) ----
// wfrag[((mt*4+ks)*64 + l)*8 + j] = W[o=16mt+(l&15)][c=32ks+8*(l>>4)+j]
// (this gather serves as the B-fragment order too: B[k=c][col=o])
__global__ __launch_bounds__(256) void k_pre(
    const float* __restrict__ w_qk, unsigned short* __restrict__ wfrag,
    float* __restrict__ kvz) {
    const int t = threadIdx.x;
    if (blockIdx.x < 128) {
        int idx = blockIdx.x * 256 + t;          // < 32768
        int j  = idx & 7;
        int l  = (idx >> 3) & 63;
        int ks = (idx >> 9) & 3;
        int mt = idx >> 11;
        int o = mt * 16 + (l & 15);
        int c = ks * 32 + (l >> 4) * 8 + j;
        wfrag[idx] = f2bf(w_qk[o * 128 + c]);
    } else {
        int i = (blockIdx.x - 128) * 256 + t;    // 528*256 = 135168 exactly
        kvz[i] = 0.0f;
    }
}

// ---- fused qk GEMM (swapped operands: out[n][o]) + elu + kv/ksum ----
// 2 n-tiles (64 px each) per block; kv/ksum accumulate in regs across tiles.
// Xn[n][c] bf16 stride 144, XOR-swizzled (byte ^= (n&7)<<4) -> conflict-free
// b128 A-frag reads. q written straight to global (b64), k to Klds (b64).
__device__ __forceinline__ void main_dev(
    const float* __restrict__ x, const unsigned short* __restrict__ wfrag,
    const float* __restrict__ b_qk,
    unsigned short* __restrict__ q_ws, float* __restrict__ kv_g,
    float* __restrict__ ks_g,
    unsigned short* Xn, unsigned short* Klds, int jb, int b) {

    const int t  = threadIdx.x;
    const int w  = t >> 6, l = t & 63, nn = l & 15, q = l >> 4;
    const float* xa = x + ((long long)(b * Cn + M0)) * HWn;

    f32x4 akv[2][2] = {};        // kv accum across tiles [d-tile][e-tile]
    float ksp[4] = {0.f, 0.f, 0.f, 0.f};
    const int ntile0 = jb * 2;
    const int ntcnt  = (ntile0 + 1 < 49) ? 2 : 1;

    for (int tt = 0; tt < ntcnt; ++tt) {
        const int n0 = (ntile0 + tt) * 64;

        // ---- stage: Xn[n][c] bf16, b64 writes, swizzled ----
        {
            const int c4 = (t & 31) * 4, no = t >> 5;   // n = no*8 + i
            float rows[4][8];
            #pragma unroll
            for (int cc = 0; cc < 4; ++cc) {
                *(float4*)(rows[cc])     = *(const float4*)(xa + (long long)(c4 + cc) * HWn + n0 + no * 8);
                *(float4*)(rows[cc] + 4) = *(const float4*)(xa + (long long)(c4 + cc) * HWn + n0 + no * 8 + 4);
            }
            #pragma unroll
            for (int i = 0; i < 8; ++i) {
                const int n = no * 8 + i;
                unsigned int lo = (unsigned int)f2bf(rows[0][i]) | ((unsigned int)f2bf(rows[1][i]) << 16);
                unsigned int hi = (unsigned int)f2bf(rows[2][i]) | ((unsigned int)f2bf(rows[3][i]) << 16);
                int off = (n * 144 + c4) * 2;
                off ^= ((n & 7) << 4);
                *(uint2*)((char*)Xn + off) = make_uint2(lo, hi);
            }
        }
        __syncthreads();

        // ---- GEMM: acc[i_n][i_o], A = X-frag, B = W-frag ----
        f32x4 acc[4][4] = {};
        #pragma unroll
        for (int ks = 0; ks < 4; ++ks) {
            bf16x8 bq[4];
            #pragma unroll
            for (int in = 0; in < 4; ++in) {
                int off = ((in * 16 + nn) * 144 + ks * 32 + q * 8) * 2;
                off ^= ((nn & 7) << 4);
                bq[in] = *(const bf16x8*)((const char*)Xn + off);
            }
            #pragma unroll
            for (int io = 0; io < 4; ++io) {
                const int mt = 4 * w + io;
                bf16x8 aq = *(const bf16x8*)(wfrag + ((mt * 4 + ks) * 64 + l) * 8);
                #pragma unroll
                for (int in = 0; in < 4; ++in)
                    acc[in][io] = __builtin_amdgcn_mfma_f32_16x16x32_bf16(bq[in], aq, acc[in][io], 0, 0, 0);
            }
        }

        // ---- epilogue: lane holds 4 consecutive n (r=0..3) per o ----
        if (w < 2) {
            #pragma unroll
            for (int io = 0; io < 4; ++io) {
                const int o = w * 64 + io * 16 + nn;
                const float bias = b_qk[o];
                unsigned short* qb = q_ws + ((long long)(b * GCn + o)) * HWn + n0 + q * 4;
                #pragma unroll
                for (int in = 0; in < 4; ++in) {
                    unsigned int lo = (unsigned int)f2bf(act_elu1(acc[in][io][0] + bias)) |
                                      ((unsigned int)f2bf(act_elu1(acc[in][io][1] + bias)) << 16);
                    unsigned int hi = (unsigned int)f2bf(act_elu1(acc[in][io][2] + bias)) |
                                      ((unsigned int)f2bf(act_elu1(acc[in][io][3] + bias)) << 16);
                    *(uint2*)(qb + in * 16) = make_uint2(lo, hi);
                }
            }
        } else {
            #pragma unroll
            for (int io = 0; io < 4; ++io) {
                const int krow = (w - 2) * 64 + io * 16 + nn;
                const float bias = b_qk[128 + krow];
                #pragma unroll
                for (int in = 0; in < 4; ++in) {
                    const float e0 = act_elu1(acc[in][io][0] + bias);
                    const float e1 = act_elu1(acc[in][io][1] + bias);
                    const float e2 = act_elu1(acc[in][io][2] + bias);
                    const float e3 = act_elu1(acc[in][io][3] + bias);
                    ksp[io] += (e0 + e1) + (e2 + e3);
                    unsigned int lo = (unsigned int)f2bf(e0) | ((unsigned int)f2bf(e1) << 16);
                    unsigned int hi = (unsigned int)f2bf(e2) | ((unsigned int)f2bf(e3) << 16);
                    *(uint2*)(Klds + krow * 72 + in * 16 + q * 4) = make_uint2(lo, hi);
                }
            }
        }
        __syncthreads();

        // ---- kv accumulate: wave w = head h; v from global (L2-hot) ----
        {
            const int h = w;
            #pragma unroll
            for (int kt = 0; kt < 2; ++kt) {
                bf16x8 af0 = *(const bf16x8*)(Klds + (h * 32 + nn) * 72 + kt * 32 + q * 8);
                bf16x8 af1 = *(const bf16x8*)(Klds + (h * 32 + 16 + nn) * 72 + kt * 32 + q * 8);
                #pragma unroll
                for (int vt = 0; vt < 2; ++vt) {
                    const float* vsrc = xa + (long long)(h * 32 + vt * 16 + nn) * HWn + n0 + kt * 32 + q * 8;
                    float4 v0 = *(const float4*)(vsrc);
                    float4 v1 = *(const float4*)(vsrc + 4);
                    short tb[8];
                    tb[0] = (short)f2bf(v0.x); tb[1] = (short)f2bf(v0.y);
                    tb[2] = (short)f2bf(v0.z); tb[3] = (short)f2bf(v0.w);
                    tb[4] = (short)f2bf(v1.x); tb[5] = (short)f2bf(v1.y);
                    tb[6] = (short)f2bf(v1.z); tb[7] = (short)f2bf(v1.w);
                    bf16x8 bv = *(bf16x8*)tb;
                    akv[0][vt] = __builtin_amdgcn_mfma_f32_16x16x32_bf16(af0, bv, akv[0][vt], 0, 0, 0);
                    akv[1][vt] = __builtin_amdgcn_mfma_f32_16x16x32_bf16(af1, bv, akv[1][vt], 0, 0, 0);
                }
            }
        }
        // next tile's stage overwrites Xn: all Xn reads finished before the
        // epilogue barrier; Klds overwrite happens after the next barrier.
    }

    // ---- combine: atomics (once per block, both tiles accumulated) ----
    const int bh = b * 4 + w;
    #pragma unroll
    for (int mt = 0; mt < 2; ++mt)
        #pragma unroll
        for (int vt = 0; vt < 2; ++vt)
            #pragma unroll
            for (int r = 0; r < 4; ++r)
                atomicAdd(&kv_g[(bh << 10) + (mt * 16 + q * 4 + r) * 32 + vt * 16 + nn],
                          akv[mt][vt][r]);
    if (w >= 2) {
        #pragma unroll
        for (int io = 0; io < 4; ++io) {
            float s = ksp[io];
            s += __shfl_xor(s, 16, 64);
            s += __shfl_xor(s, 32, 64);
            if (q == 0) {
                const int krow = (w - 2) * 64 + io * 16 + nn;
                atomicAdd(&ks_g[b * 128 + krow], s);
            }
        }
    }
}

// ---- k2: main blocks (0..799) + mem-copy blocks (800..2847) ----
__global__ __launch_bounds__(256) void k_maincopy(
    const float* __restrict__ x, const unsigned short* __restrict__ wfrag,
    const float* __restrict__ b_qk,
    unsigned short* __restrict__ q_ws, float* __restrict__ kv_g,
    float* __restrict__ ks_g, float* __restrict__ mem_out) {

    __shared__ __align__(16) unsigned char smem[36864];  // Xn 18432 | Klds 18432
    const int bid = blockIdx.x;
    if (bid < 800) {
        main_dev(x, wfrag, b_qk, q_ws, kv_g, ks_g,
                 (unsigned short*)smem, (unsigned short*)(smem + 18432),
                 bid % 25, bid / 25);
    } else {
        const int r = bid - 800;                 // 2048 copy blocks
        for (int i4 = r * 256 + (int)threadIdx.x; i4 < 3211264; i4 += 2048 * 256) {
            int b  = i4 / 100352;
            int rr = i4 - b * 100352;
            ((float4*)mem_out)[i4] = ((const float4*)x)[(long long)b * 401408 + rr];
        }
    }
}

// ---- att epilogue: 2 pixels/thread, q bf16, kv broadcast from LDS ----
__device__ __forceinline__ void att_dev(
    const unsigned short* __restrict__ q_ws, const float* __restrict__ kv_g,
    const float* __restrict__ ks_g, float* __restrict__ feats,
    float* kvl, float* kml, int gx, int h, int b) {

    const int t = threadIdx.x;
    const int bh = b * 4 + h;
    const float inv = 1.0f / 3136.0f;
    #pragma unroll
    for (int p = 0; p < 4; ++p) kvl[t + p * 256] = kv_g[(bh << 10) + t + p * 256] * inv;
    if (t < 32) kml[t] = ks_g[bh * 32 + t] * inv;
    __syncthreads();

    const int n2 = gx * 256 + t;
    if (n2 >= 1568) return;
    const unsigned short* qp = q_ws + ((long long)(b * GCn + h * 32)) * HWn + n2 * 2;
    float a0[32], a1[32];
    float z0 = 1e-6f, z1 = 1e-6f;
    #pragma unroll
    for (int e = 0; e < 32; ++e) { a0[e] = 0.f; a1[e] = 0.f; }
    #pragma unroll 4
    for (int d = 0; d < 32; ++d) {
        const unsigned int qq = *(const unsigned int*)(qp + (long long)d * HWn);
        const float q0 = bf2f((unsigned short)qq);
        const float q1 = bf2f((unsigned short)(qq >> 16));
        z0 = __builtin_fmaf(q0, kml[d], z0);
        z1 = __builtin_fmaf(q1, kml[d], z1);
        #pragma unroll
        for (int e = 0; e < 32; ++e) {
            const float kv = kvl[d * 32 + e];
            a0[e] = __builtin_fmaf(q0, kv, a0[e]);
            a1[e] = __builtin_fmaf(q1, kv, a1[e]);
        }
    }
    z0 = 1.f / z0; z1 = 1.f / z1;
    float* op = feats + ((long long)(b * 384 + h * 32)) * HWn + n2 * 2;
    #pragma unroll
    for (int e = 0; e < 32; ++e)
        *(float2*)(op + (long long)e * HWn) = make_float2(a0[e] * z0, a1[e] * z1);
}

// ---- depthwise conv: 2 channels/block, 64-word rows, XOR chunk swizzle,
//      2-row x 8-wide items (KS+1 row-reads serve 2 output rows) ----
template<int KS, int PAD, int CIN>
__device__ __forceinline__ void dwconv2_dev(
    const float* __restrict__ x, const float* __restrict__ wg,
    const float* __restrict__ bg, float* __restrict__ feats,
    float* P, int cp, int b) {

    const int t = threadIdx.x;
    constexpr int ROWS = 56 + 2 * PAD;           // 58 (3x3) / 62 (7x7)
    constexpr int PL = ROWS * 64;                // plane floats
    const int c0 = cp * 2;

    const float4 z4 = make_float4(0.f, 0.f, 0.f, 0.f);
    for (int i = t; i < (2 * PL) >> 2; i += 256) ((float4*)P)[i] = z4;
    __syncthreads();

    for (int i = t; i < 1568; i += 256) {        // stage 2 planes, swizzled
        const int ch = (i >= 784) ? 1 : 0;
        const int r  = i - ch * 784;
        const int y  = r / 14, k = r - y * 14;   // input row y, px 4k..4k+3
        const float* in = x + ((long long)(b * Cn + CIN + c0 + ch)) * HWn + y * 56 + k * 4;
        const int row = y + PAD;
        const int ck  = (1 + k) ^ (row & 7);     // word (4+4k)>>2, XOR-swizzled
        *(float4*)(P + ch * PL + row * 64 + ck * 4) = *(const float4*)in;
    }
    __syncthreads();

    for (int item = t; item < 392; item += 256) {   // 2ch x 28 row-pairs x 7 octs
        const int ch = (item >= 196) ? 1 : 0;
        const int r  = item - ch * 196;
        const int ri = r / 7, m = r - ri * 7;
        const int y0 = ri * 2;
        const int xo = m * 8;
        const float* wp = wg + (c0 + ch) * KS * KS;
        const float bias = bg[c0 + ch];
        const float* Pc = P + ch * PL;
        float* op = feats + ((long long)(b * 384 + (CIN - 128) + c0 + ch)) * HWn;

        float a0[8], a1[8];
        #pragma unroll
        for (int j = 0; j < 8; ++j) { a0[j] = bias; a1[j] = bias; }
        #pragma unroll
        for (int dy = 0; dy <= KS; ++dy) {
            const int row = y0 + dy;
            float rr[16];
            #pragma unroll
            for (int u = 0; u < 4; ++u) {
                const int ck = ((xo >> 2) + u) ^ (row & 7);
                *(float4*)(rr + 4 * u) = *(const float4*)(Pc + row * 64 + ck * 4);
            }
            if (dy < KS) {
                #pragma unroll
                for (int dx = 0; dx < KS; ++dx) {
                    const float wv = wp[dy * KS + dx];
                    #pragma unroll
                    for (int j = 0; j < 8; ++j)
                        a0[j] = __builtin_fmaf(wv, rr[j + dx + 4 - PAD], a0[j]);
                }
            }
            if (dy >= 1) {
                #pragma unroll
                for (int dx = 0; dx < KS; ++dx) {
                    const float wv = wp[(dy - 1) * KS + dx];
                    #pragma unroll
                    for (int j = 0; j < 8; ++j)
                        a1[j] = __builtin_fmaf(wv, rr[j + dx + 4 - PAD], a1[j]);
                }
            }
        }
        *(float4*)(op + y0 * 56 + xo)           = make_float4(a0[0], a0[1], a0[2], a0[3]);
        *(float4*)(op + y0 * 56 + xo + 4)       = make_float4(a0[4], a0[5], a0[6], a0[7]);
        *(float4*)(op + (y0 + 1) * 56 + xo)     = make_float4(a1[0], a1[1], a1[2], a1[3]);
        *(float4*)(op + (y0 + 1) * 56 + xo + 4) = make_float4(a1[4], a1[5], a1[6], a1[7]);
    }
}

// ---- k3: dw2 (0..2047) | dw1 (2048..4095) | att (4096..4991) ----
__global__ __launch_bounds__(256) void k_post2(
    const float* __restrict__ x,
    const unsigned short* __restrict__ q_ws, const float* __restrict__ kv_g,
    const float* __restrict__ ks_g,
    const float* __restrict__ w_dw1, const float* __restrict__ b_dw1,
    const float* __restrict__ w_dw2, const float* __restrict__ b_dw2,
    float* __restrict__ feats) {

    __shared__ __align__(16) float smem[2 * 62 * 64];   // 31744 B
    const int bid = blockIdx.x;

    if (bid < 2048) {
        dwconv2_dev<7, 3, 384>(x, w_dw2, b_dw2, feats, smem, bid & 63, bid >> 6);
    } else if (bid < 4096) {
        const int r = bid - 2048;
        dwconv2_dev<3, 1, 256>(x, w_dw1, b_dw1, feats, smem, r & 63, r >> 6);
    } else {
        const int r = bid - 4096;                // 896 att blocks
        const int b = r / 28, rem = r % 28;
        att_dev(q_ws, kv_g, ks_g, feats, smem, smem + 1024, rem % 7, rem / 7, b);
    }
}

extern "C" void kernel_launch(void* const* d_in, const int* in_sizes, int n_in,
                              void* d_out, int out_size, void* d_ws, size_t ws_size,
                              hipStream_t stream) {
    const float* x     = (const float*)d_in[0];
    const float* w_dw1 = (const float*)d_in[1];
    const float* b_dw1 = (const float*)d_in[2];
    const float* w_dw2 = (const float*)d_in[3];
    const float* b_dw2 = (const float*)d_in[4];
    const float* w_qk  = (const float*)d_in[5];
    const float* b_qk  = (const float*)d_in[6];
    float* out = (float*)d_out;

    // ws layout: q bf16 | kv f32 | ksum f32 | wfrag bf16
    unsigned short* q_ws = (unsigned short*)d_ws;
    float* kv_g = (float*)(q_ws + (long long)Q_ELEMS);
    float* ks_g = kv_g + KV_ELEMS;
    unsigned short* wfrag = (unsigned short*)(ks_g + KS_ELEMS);

    float* mem_out = out;
    float* feats   = out + (long long)Bn * GCn * HWn;

    k_pre     <<<656, 256, 0, stream>>>(w_qk, wfrag, kv_g);
    k_maincopy<<<2848, 256, 0, stream>>>(x, wfrag, b_qk, q_ws, kv_g, ks_g, mem_out);
    k_post2   <<<4992, 256, 0, stream>>>(x, q_ws, kv_g, ks_g,
                                         w_dw1, b_dw1, w_dw2, b_dw2, feats);
}